// Round 2
// baseline (3281.359 us; speedup 1.0000x reference)
//
#include <hip/hip_runtime.h>

#define BT   4      // batch tile per block
#define HID  64
#define G4   256    // 4*HID
#define SEQ  512
#define NOUT 12

__device__ __forceinline__ float sigf(float x)  { return 1.f / (1.f + __expf(-x)); }
__device__ __forceinline__ float tanhf_fast(float x) { return 1.f - 2.f / (1.f + __expf(2.f * x)); }

__global__ __launch_bounds__(256, 1) void lstm2_fused(
    const float* __restrict__ x,      // [B, SEQ, 1]
    const float* __restrict__ w_ih0,  // [256, 1]
    const float* __restrict__ w_hh0,  // [256, 64]
    const float* __restrict__ b_ih0,  // [256]
    const float* __restrict__ b_hh0,  // [256]
    const float* __restrict__ w_ih1,  // [256, 64]
    const float* __restrict__ w_hh1,  // [256, 64]
    const float* __restrict__ b_ih1,  // [256]
    const float* __restrict__ b_hh1,  // [256]
    const float* __restrict__ fc_w,   // [12, 64]
    const float* __restrict__ fc_b,   // [12]
    float* __restrict__ out)          // [B, 12]
{
    __shared__ float xs[BT][SEQ];    // 8 KB
    __shared__ float h0s[BT][HID];   // 1 KB
    __shared__ float h1s[BT][HID];   // 1 KB
    __shared__ float gs[BT][G4];     // 4 KB

    const int tid = threadIdx.x;
    const int g   = tid;              // gate row owned by this thread
    const int b0  = blockIdx.x * BT;

    // ---- loop-invariant weights into registers (192 VGPRs) ----
    float w0[HID], wi1[HID], w1[HID];
#pragma unroll
    for (int k = 0; k < HID; ++k) {
        w0[k]  = w_hh0[g * HID + k];
        wi1[k] = w_ih1[g * HID + k];
        w1[k]  = w_hh1[g * HID + k];
    }
    const float wih0g = w_ih0[g];                    // input size == 1
    const float bias0 = b_ih0[g] + b_hh0[g];
    const float bias1 = b_ih1[g] + b_hh1[g];

    // ---- stage this block's x tile into LDS ----
    for (int i = tid; i < BT * SEQ; i += 256) {
        int b = i >> 9, t = i & (SEQ - 1);
        xs[b][t] = x[(size_t)(b0 + b) * SEQ + t];
    }
    for (int i = tid; i < BT * HID; i += 256) {
        ((float*)h0s)[i] = 0.f;
        ((float*)h1s)[i] = 0.f;
    }
    // elementwise-phase identity of this thread
    const int eb = tid >> 6;     // batch in tile
    const int ej = tid & 63;     // hidden unit
    float c0 = 0.f, c1 = 0.f;
    __syncthreads();

    for (int t = 0; t < SEQ; ++t) {
        // ===== layer 0: gates0[b][g] = bias0 + x*w_ih0[g] + h0 . w_hh0[g] =====
        float a[BT];
#pragma unroll
        for (int b = 0; b < BT; ++b) a[b] = fmaf(xs[b][t], wih0g, bias0);
#pragma unroll
        for (int b = 0; b < BT; ++b) {
#pragma unroll
            for (int k = 0; k < HID; k += 4) {
                float4 hv = *(const float4*)&h0s[b][k];   // wave-uniform broadcast read
                a[b] = fmaf(hv.x, w0[k + 0], a[b]);
                a[b] = fmaf(hv.y, w0[k + 1], a[b]);
                a[b] = fmaf(hv.z, w0[k + 2], a[b]);
                a[b] = fmaf(hv.w, w0[k + 3], a[b]);
            }
        }
#pragma unroll
        for (int b = 0; b < BT; ++b) gs[b][g] = a[b];
        __syncthreads();

        // ===== elementwise 0 (one (b,j) pair per thread; c0 in registers) =====
        {
            float ig = sigf(gs[eb][ej]);
            float fg = sigf(gs[eb][64 + ej]);
            float gg = tanhf_fast(gs[eb][128 + ej]);
            float og = sigf(gs[eb][192 + ej]);
            c0 = fg * c0 + ig * gg;
            h0s[eb][ej] = og * tanhf_fast(c0);
        }
        __syncthreads();

        // ===== layer 1: gates1[b][g] = bias1 + h0_new . w_ih1[g] + h1_old . w_hh1[g] =====
#pragma unroll
        for (int b = 0; b < BT; ++b) a[b] = bias1;
#pragma unroll
        for (int b = 0; b < BT; ++b) {
#pragma unroll
            for (int k = 0; k < HID; k += 4) {
                float4 hv = *(const float4*)&h0s[b][k];
                a[b] = fmaf(hv.x, wi1[k + 0], a[b]);
                a[b] = fmaf(hv.y, wi1[k + 1], a[b]);
                a[b] = fmaf(hv.z, wi1[k + 2], a[b]);
                a[b] = fmaf(hv.w, wi1[k + 3], a[b]);
                float4 h1v = *(const float4*)&h1s[b][k];
                a[b] = fmaf(h1v.x, w1[k + 0], a[b]);
                a[b] = fmaf(h1v.y, w1[k + 1], a[b]);
                a[b] = fmaf(h1v.z, w1[k + 2], a[b]);
                a[b] = fmaf(h1v.w, w1[k + 3], a[b]);
            }
        }
#pragma unroll
        for (int b = 0; b < BT; ++b) gs[b][g] = a[b];
        __syncthreads();

        // ===== elementwise 1 =====
        {
            float ig = sigf(gs[eb][ej]);
            float fg = sigf(gs[eb][64 + ej]);
            float gg = tanhf_fast(gs[eb][128 + ej]);
            float og = sigf(gs[eb][192 + ej]);
            c1 = fg * c1 + ig * gg;
            h1s[eb][ej] = og * tanhf_fast(c1);
        }
        __syncthreads();
    }

    // ===== final projection: out[b][o] = fc_b[o] + h1 . fc_w[o] =====
    if (tid < BT * NOUT) {
        int b = tid / NOUT, o = tid % NOUT;
        float acc = fc_b[o];
#pragma unroll
        for (int j = 0; j < HID; ++j)
            acc = fmaf(fc_w[o * HID + j], h1s[b][j], acc);
        out[(size_t)(b0 + b) * NOUT + o] = acc;
    }
}

extern "C" void kernel_launch(void* const* d_in, const int* in_sizes, int n_in,
                              void* d_out, int out_size, void* d_ws, size_t ws_size,
                              hipStream_t stream) {
    const float* x     = (const float*)d_in[0];
    const float* w_ih0 = (const float*)d_in[1];
    const float* w_hh0 = (const float*)d_in[2];
    const float* b_ih0 = (const float*)d_in[3];
    const float* b_hh0 = (const float*)d_in[4];
    const float* w_ih1 = (const float*)d_in[5];
    const float* w_hh1 = (const float*)d_in[6];
    const float* b_ih1 = (const float*)d_in[7];
    const float* b_hh1 = (const float*)d_in[8];
    const float* fc_w  = (const float*)d_in[9];
    const float* fc_b  = (const float*)d_in[10];

    const int B = in_sizes[0] / SEQ;          // 2048
    dim3 grid(B / BT);                        // 512 blocks -> 2 blocks/CU
    lstm2_fused<<<grid, 256, 0, stream>>>(x, w_ih0, w_hh0, b_ih0, b_hh0,
                                          w_ih1, w_hh1, b_ih1, b_hh1,
                                          fc_w, fc_b, (float*)d_out);
}

// Round 3
// 2086.515 us; speedup vs baseline: 1.5727x; 1.5727x over previous
//
#include <hip/hip_runtime.h>

#define BT   4      // batch tile per block
#define HID  64
#define G4   256    // 4*HID
#define SEQ  512
#define NOUT 12

typedef float v16f __attribute__((ext_vector_type(16)));

__device__ __forceinline__ float sigf(float x)  { return 1.f / (1.f + __expf(-x)); }
__device__ __forceinline__ float tanhf_fast(float x) { return 1.f - 2.f / (1.f + __expf(2.f * x)); }

// Load 64 weights (row g of a [256,64] matrix) into four v16f SSA vectors.
#define LOAD_ROW(M, V0, V1, V2, V3)                                        \
    {                                                                      \
        const float4* p = (const float4*)&M[g * HID];                      \
        _Pragma("unroll")                                                  \
        for (int c = 0; c < 4; ++c) {                                      \
            v16f& D = (c == 0) ? V0 : (c == 1) ? V1 : (c == 2) ? V2 : V3;  \
            _Pragma("unroll")                                              \
            for (int j = 0; j < 4; ++j) {                                  \
                float4 q = p[c * 4 + j];                                   \
                D[4 * j + 0] = q.x; D[4 * j + 1] = q.y;                    \
                D[4 * j + 2] = q.z; D[4 * j + 3] = q.w;                    \
            }                                                              \
        }                                                                  \
    }

__global__ void __launch_bounds__(256) __attribute__((amdgpu_waves_per_eu(2, 2)))
lstm2_fused(
    const float* __restrict__ x,      // [B, SEQ, 1]
    const float* __restrict__ w_ih0,  // [256, 1]
    const float* __restrict__ w_hh0,  // [256, 64]
    const float* __restrict__ b_ih0,  // [256]
    const float* __restrict__ b_hh0,  // [256]
    const float* __restrict__ w_ih1,  // [256, 64]
    const float* __restrict__ w_hh1,  // [256, 64]
    const float* __restrict__ b_ih1,  // [256]
    const float* __restrict__ b_hh1,  // [256]
    const float* __restrict__ fc_w,   // [12, 64]
    const float* __restrict__ fc_b,   // [12]
    float* __restrict__ out)          // [B, 12]
{
    __shared__ float xs[BT][SEQ];    // 8 KB
    __shared__ float h0s[BT][HID];   // 1 KB
    __shared__ float h1s[BT][HID];   // 1 KB
    __shared__ float gs[BT][G4];     // 4 KB

    const int tid = threadIdx.x;
    const int g   = tid;              // gate row owned by this thread
    const int b0  = blockIdx.x * BT;

    // ---- loop-invariant weights as SSA vectors (12 x v16f = 192 VGPRs) ----
    v16f w0_0 = {}, w0_1 = {}, w0_2 = {}, w0_3 = {};
    v16f wi_0 = {}, wi_1 = {}, wi_2 = {}, wi_3 = {};
    v16f w1_0 = {}, w1_1 = {}, w1_2 = {}, w1_3 = {};
    LOAD_ROW(w_hh0, w0_0, w0_1, w0_2, w0_3);
    LOAD_ROW(w_ih1, wi_0, wi_1, wi_2, wi_3);
    LOAD_ROW(w_hh1, w1_0, w1_1, w1_2, w1_3);

    const float wih0g = w_ih0[g];                    // input size == 1
    const float bias0 = b_ih0[g] + b_hh0[g];
    const float bias1 = b_ih1[g] + b_hh1[g];

    // ---- stage this block's x tile into LDS ----
    for (int i = tid; i < BT * SEQ; i += 256) {
        int b = i >> 9, t = i & (SEQ - 1);
        xs[b][t] = x[(size_t)(b0 + b) * SEQ + t];
    }
    for (int i = tid; i < BT * HID; i += 256) {
        ((float*)h0s)[i] = 0.f;
        ((float*)h1s)[i] = 0.f;
    }
    const int eb = tid >> 6;     // batch in tile (elementwise phase)
    const int ej = tid & 63;     // hidden unit   (elementwise phase)
    float c0 = 0.f, c1 = 0.f;
    __syncthreads();

    for (int t = 0; t < SEQ; ++t) {
        float a[BT];
        // ===== layer 0: gates0[b][g] = bias0 + x*w_ih0[g] + h0 . w_hh0[g] =====
#pragma unroll
        for (int b = 0; b < BT; ++b) a[b] = fmaf(xs[b][t], wih0g, bias0);
#pragma unroll
        for (int c = 0; c < 4; ++c) {
            v16f& W0c = (c == 0) ? w0_0 : (c == 1) ? w0_1 : (c == 2) ? w0_2 : w0_3;
#pragma unroll
            for (int i = 0; i < 16; i += 4) {
#pragma unroll
                for (int b = 0; b < BT; ++b) {
                    float4 hv = *(const float4*)&h0s[b][c * 16 + i];  // uniform broadcast
                    a[b] = fmaf(hv.x, W0c[i + 0], a[b]);
                    a[b] = fmaf(hv.y, W0c[i + 1], a[b]);
                    a[b] = fmaf(hv.z, W0c[i + 2], a[b]);
                    a[b] = fmaf(hv.w, W0c[i + 3], a[b]);
                }
            }
        }
#pragma unroll
        for (int b = 0; b < BT; ++b) gs[b][g] = a[b];
        __syncthreads();

        // ===== elementwise 0 (one (b,j) pair per thread; c0 in registers) =====
        {
            float ig = sigf(gs[eb][ej]);
            float fg = sigf(gs[eb][64 + ej]);
            float gg = tanhf_fast(gs[eb][128 + ej]);
            float og = sigf(gs[eb][192 + ej]);
            c0 = fg * c0 + ig * gg;
            h0s[eb][ej] = og * tanhf_fast(c0);
        }
        __syncthreads();

        // ===== layer 1: gates1[b][g] = bias1 + h0_new . w_ih1[g] + h1_old . w_hh1[g] =====
#pragma unroll
        for (int b = 0; b < BT; ++b) a[b] = bias1;
#pragma unroll
        for (int c = 0; c < 4; ++c) {
            v16f& WIc = (c == 0) ? wi_0 : (c == 1) ? wi_1 : (c == 2) ? wi_2 : wi_3;
            v16f& W1c = (c == 0) ? w1_0 : (c == 1) ? w1_1 : (c == 2) ? w1_2 : w1_3;
#pragma unroll
            for (int i = 0; i < 16; i += 4) {
#pragma unroll
                for (int b = 0; b < BT; ++b) {
                    float4 hv  = *(const float4*)&h0s[b][c * 16 + i];
                    float4 h1v = *(const float4*)&h1s[b][c * 16 + i];
                    a[b] = fmaf(hv.x,  WIc[i + 0], a[b]);
                    a[b] = fmaf(hv.y,  WIc[i + 1], a[b]);
                    a[b] = fmaf(hv.z,  WIc[i + 2], a[b]);
                    a[b] = fmaf(hv.w,  WIc[i + 3], a[b]);
                    a[b] = fmaf(h1v.x, W1c[i + 0], a[b]);
                    a[b] = fmaf(h1v.y, W1c[i + 1], a[b]);
                    a[b] = fmaf(h1v.z, W1c[i + 2], a[b]);
                    a[b] = fmaf(h1v.w, W1c[i + 3], a[b]);
                }
            }
        }
#pragma unroll
        for (int b = 0; b < BT; ++b) gs[b][g] = a[b];
        __syncthreads();

        // ===== elementwise 1 =====
        {
            float ig = sigf(gs[eb][ej]);
            float fg = sigf(gs[eb][64 + ej]);
            float gg = tanhf_fast(gs[eb][128 + ej]);
            float og = sigf(gs[eb][192 + ej]);
            c1 = fg * c1 + ig * gg;
            h1s[eb][ej] = og * tanhf_fast(c1);
        }
        __syncthreads();
    }

    // ===== final projection: out[b][o] = fc_b[o] + h1 . fc_w[o] =====
    if (tid < BT * NOUT) {
        int b = tid / NOUT, o = tid % NOUT;
        float acc = fc_b[o];
#pragma unroll
        for (int j = 0; j < HID; ++j)
            acc = fmaf(fc_w[o * HID + j], h1s[b][j], acc);
        out[(size_t)(b0 + b) * NOUT + o] = acc;
    }
}

extern "C" void kernel_launch(void* const* d_in, const int* in_sizes, int n_in,
                              void* d_out, int out_size, void* d_ws, size_t ws_size,
                              hipStream_t stream) {
    const float* x     = (const float*)d_in[0];
    const float* w_ih0 = (const float*)d_in[1];
    const float* w_hh0 = (const float*)d_in[2];
    const float* b_ih0 = (const float*)d_in[3];
    const float* b_hh0 = (const float*)d_in[4];
    const float* w_ih1 = (const float*)d_in[5];
    const float* w_hh1 = (const float*)d_in[6];
    const float* b_ih1 = (const float*)d_in[7];
    const float* b_hh1 = (const float*)d_in[8];
    const float* fc_w  = (const float*)d_in[9];
    const float* fc_b  = (const float*)d_in[10];

    const int B = in_sizes[0] / SEQ;          // 2048
    dim3 grid(B / BT);                        // 512 blocks -> 2 blocks/CU
    lstm2_fused<<<grid, 256, 0, stream>>>(x, w_ih0, w_hh0, b_ih0, b_hh0,
                                          w_ih1, w_hh1, b_ih1, b_hh1,
                                          fc_w, fc_b, (float*)d_out);
}